// Round 2
// baseline (785.715 us; speedup 1.0000x reference)
//
#include <hip/hip_runtime.h>
#include <math.h>

// ---------------------------------------------------------------------------
// NeuralNet_62045097558546 on MI355X (gfx950)
// 3x (GEMM+bias+ReLU+cmax -> soft-topk mask) -> GEMM+bias
// M=4096, d_in=1024, d_h=500 (padded 512), d_out=10, K(topk)=400, eps=0.1
//
// GEMM design: 256-thr block = 4 waves; each wave computes the FULL 64x64
// output tile over ITS OWN quarter of K (in-block split-K) with a private
// LDS staging region -> the K-loop is completely barrier-free (wave-
// synchronous). 8x8 per-thread fragments (64 fma per 4 ds_read_b128).
// Epilogue: cross-wave reduce in LDS + bias + relu + atomicMax(cmax) fused.
// ---------------------------------------------------------------------------

#define LDT   68      // LDS staging stride (floats): 64 + 4 pad, keeps b128 align
#define REDLD 36      // reduction region stride: 32 + 4 pad

__device__ __forceinline__ float relu_cost_max(float h) {
  const float hm = h - 1.0f;
  return fmaxf(h * h, hm * hm);
}

__global__ __launch_bounds__(256, 2) void gemm_fused(
    const float* __restrict__ A, int lda, int K,
    const float* __restrict__ Bp,        // [K][512], zero-padded cols (and rows)
    const float* __restrict__ bias,      // [500]
    float* __restrict__ H,               // [4096][512] output, pad cols = 0
    unsigned int* __restrict__ cmax)
{
  // smem union: staging (4 waves x (As[16][68] + Bs[16][68]) = 8704 floats)
  //             reduction red[4][64][36] = 9216 floats
  __shared__ float smem[9216];

  const int tid  = threadIdx.x;
  const int w    = tid >> 6;
  const int lane = tid & 63;
  const int tx   = lane & 7;
  const int ty   = lane >> 3;
  const int row0 = blockIdx.y * 64;
  const int col0 = blockIdx.x * 64;

  float* As = smem + w * 2176;
  float* Bs = As + 1088;

  const int chunk = K >> 2;     // per-wave K range
  const int kb    = w * chunk;
  const int nt    = chunk >> 4; // 16-wide K tiles

  // staging lane mapping
  const int ar  = lane >> 2;          // A row within 16-row group
  const int akq = (lane & 3) * 4;     // A k offset {0,4,8,12}
  const int bkr = lane >> 4;          // B k row {0..3}
  const int bc4 = (lane & 15) * 4;    // B col offset

  const float* Ab = A  + (size_t)(row0 + ar) * lda + kb + akq;
  const float* Bb = Bp + (size_t)(kb + bkr) * 512 + col0 + bc4;

  float4 aReg[4], bReg[4];

  // ---- load tile 0 ----
  #pragma unroll
  for (int q = 0; q < 4; ++q) aReg[q] = *(const float4*)(Ab + (size_t)16 * q * lda);
  #pragma unroll
  for (int q = 0; q < 4; ++q) bReg[q] = *(const float4*)(Bb + (size_t)4 * q * 512);

  // ---- store tile 0 (A transposed to As[k][m], B linear) ----
  #pragma unroll
  for (int q = 0; q < 4; ++q) {
    float* p = As + akq * LDT + ar + 16 * q;
    p[0 * LDT] = aReg[q].x; p[1 * LDT] = aReg[q].y;
    p[2 * LDT] = aReg[q].z; p[3 * LDT] = aReg[q].w;
  }
  #pragma unroll
  for (int q = 0; q < 4; ++q)
    *(float4*)(Bs + (bkr + 4 * q) * LDT + bc4) = bReg[q];

  float acc[8][8] = {};

  for (int t = 0; t < nt; ++t) {
    const bool pre = (t + 1 < nt);
    if (pre) {
      const float* Ab2 = Ab + (size_t)16 * (t + 1);
      const float* Bb2 = Bb + (size_t)16 * (t + 1) * 512;
      #pragma unroll
      for (int q = 0; q < 4; ++q) aReg[q] = *(const float4*)(Ab2 + (size_t)16 * q * lda);
      #pragma unroll
      for (int q = 0; q < 4; ++q) bReg[q] = *(const float4*)(Bb2 + (size_t)4 * q * 512);
    }

    #pragma unroll
    for (int kk = 0; kk < 16; ++kk) {
      const float4 a0 = *(const float4*)(As + kk * LDT + ty * 8);
      const float4 a1 = *(const float4*)(As + kk * LDT + ty * 8 + 4);
      const float4 b0 = *(const float4*)(Bs + kk * LDT + tx * 8);
      const float4 b1 = *(const float4*)(Bs + kk * LDT + tx * 8 + 4);
      const float av[8] = {a0.x, a0.y, a0.z, a0.w, a1.x, a1.y, a1.z, a1.w};
      const float bv[8] = {b0.x, b0.y, b0.z, b0.w, b1.x, b1.y, b1.z, b1.w};
      #pragma unroll
      for (int i = 0; i < 8; ++i)
        #pragma unroll
        for (int j = 0; j < 8; ++j)
          acc[i][j] = fmaf(av[i], bv[j], acc[i][j]);
    }

    if (pre) {
      #pragma unroll
      for (int q = 0; q < 4; ++q) {
        float* p = As + akq * LDT + ar + 16 * q;
        p[0 * LDT] = aReg[q].x; p[1 * LDT] = aReg[q].y;
        p[2 * LDT] = aReg[q].z; p[3 * LDT] = aReg[q].w;
      }
      #pragma unroll
      for (int q = 0; q < 4; ++q)
        *(float4*)(Bs + (bkr + 4 * q) * LDT + bc4) = bReg[q];
    }
  }

  // ---- epilogue: cross-wave split-K reduce + bias + relu + cmax ----
  float* red = smem;   // [4][64][REDLD], 2 column-half passes
  float localmax = 0.0f;

  #pragma unroll
  for (int p = 0; p < 2; ++p) {
    __syncthreads();
    if ((tx >> 2) == p) {
      const int cbase = tx * 8 - p * 32;   // 0,8,16,24
      #pragma unroll
      for (int i = 0; i < 8; ++i) {
        float* dst = red + w * 2304 + (ty * 8 + i) * REDLD + cbase;
        *(float4*)dst       = make_float4(acc[i][0], acc[i][1], acc[i][2], acc[i][3]);
        *(float4*)(dst + 4) = make_float4(acc[i][4], acc[i][5], acc[i][6], acc[i][7]);
      }
    }
    __syncthreads();

    // each wave reduces rows [16w,16w+16), cols [32p,32p+32)
    const int rr = lane >> 2;           // 0..15
    const int cc = (lane & 3) * 8;      // 0,8,16,24
    const int r  = w * 16 + rr;

    float4 s0 = make_float4(0.f, 0.f, 0.f, 0.f);
    float4 s1 = make_float4(0.f, 0.f, 0.f, 0.f);
    #pragma unroll
    for (int v = 0; v < 4; ++v) {
      const float* src = red + v * 2304 + r * REDLD + cc;
      const float4 x0 = *(const float4*)src;
      const float4 x1 = *(const float4*)(src + 4);
      s0.x += x0.x; s0.y += x0.y; s0.z += x0.z; s0.w += x0.w;
      s1.x += x1.x; s1.y += x1.y; s1.z += x1.z; s1.w += x1.w;
    }

    const int cg0 = col0 + p * 32 + cc;
    float4 o0 = make_float4(0.f, 0.f, 0.f, 0.f);
    float4 o1 = make_float4(0.f, 0.f, 0.f, 0.f);
    if (cg0 < 500) {
      const float4 bb = *(const float4*)&bias[cg0];
      o0.x = fmaxf(s0.x + bb.x, 0.f); o0.y = fmaxf(s0.y + bb.y, 0.f);
      o0.z = fmaxf(s0.z + bb.z, 0.f); o0.w = fmaxf(s0.w + bb.w, 0.f);
      localmax = fmaxf(localmax, fmaxf(fmaxf(relu_cost_max(o0.x), relu_cost_max(o0.y)),
                                       fmaxf(relu_cost_max(o0.z), relu_cost_max(o0.w))));
    }
    if (cg0 + 4 < 500) {
      const float4 bb = *(const float4*)&bias[cg0 + 4];
      o1.x = fmaxf(s1.x + bb.x, 0.f); o1.y = fmaxf(s1.y + bb.y, 0.f);
      o1.z = fmaxf(s1.z + bb.z, 0.f); o1.w = fmaxf(s1.w + bb.w, 0.f);
      localmax = fmaxf(localmax, fmaxf(fmaxf(relu_cost_max(o1.x), relu_cost_max(o1.y)),
                                       fmaxf(relu_cost_max(o1.z), relu_cost_max(o1.w))));
    }
    float* Hp = H + (size_t)(row0 + r) * 512 + cg0;
    *(float4*)Hp       = o0;
    *(float4*)(Hp + 4) = o1;
  }

  #pragma unroll
  for (int off = 32; off; off >>= 1)
    localmax = fmaxf(localmax, __shfl_xor(localmax, off));
  if (lane == 0) atomicMax(cmax, __float_as_uint(localmax));
}

// Zero the three cmax accumulator slots (re-init every call: graph-replay safe).
__global__ void init_kernel(unsigned int* c)
{
  if (threadIdx.x < 3) c[threadIdx.x] = 0u;
}

// Pad a [Krows x 500] weight matrix into [KrowsPad x 512] with zeros.
__global__ __launch_bounds__(256) void pad_w_kernel(
    const float* __restrict__ W, float* __restrict__ Wp, int Krows, int KrowsPad)
{
  const int idx = blockIdx.x * blockDim.x + threadIdx.x;
  if (idx < KrowsPad * 512) {
    const int r = idx >> 9, c = idx & 511;
    Wp[idx] = (r < Krows && c < 500) ? W[r * 500 + c] : 0.0f;
  }
}

// Soft top-k (2-anchor Sinkhorn collapsed to scalar fixed point).
// One wave per row (4 rows per block). Exact recurrences:
//   R_i = exp((2h_i-1)/(0.1*cmax)); w_i = 1/(1+t R_i); A = sum_valid w_i
//   B = (500 - A)/t  =>  t <- 0.25*A*t/(500-A); mask_i = 400*w_i/A
__global__ __launch_bounds__(256) void sinkhorn_kernel(
    const float* __restrict__ H, float* __restrict__ Out,
    const unsigned int* __restrict__ cmaxp, const int* __restrict__ sparse)
{
  const int w    = threadIdx.x >> 6;
  const int lane = threadIdx.x & 63;
  const int row  = blockIdx.x * 4 + w;
  const float cmax = __uint_as_float(cmaxp[0]);
  const float s    = (float)sparse[0];
  const float inv  = 1.0f / (0.1f * cmax);

  const float* Hr = H + (size_t)row * 512;
  float h[8], R[8];
  #pragma unroll
  for (int j = 0; j < 8; ++j) {
    h[j] = Hr[lane + 64 * j];                 // pad cols read as 0
    R[j] = __expf((2.0f * h[j] - 1.0f) * inv);
  }
  const bool v7 = (lane < 52);                // lane+448 < 500

  float t = 1.0f, A = 0.0f;
  for (int it = 0; it < 50; ++it) {
    A = 0.0f;
    #pragma unroll
    for (int j = 0; j < 8; ++j) {
      float wj = __builtin_amdgcn_rcpf(fmaf(t, R[j], 1.0f));
      if (j == 7 && !v7) wj = 0.0f;
      A += wj;
    }
    #pragma unroll
    for (int off = 32; off; off >>= 1) A += __shfl_xor(A, off);
    if (it < 49) t = 0.25f * A * t * __builtin_amdgcn_rcpf(500.0f - A);
  }

  const float kA = 400.0f / A;
  float* Or = Out + (size_t)row * 512;
  #pragma unroll
  for (int j = 0; j < 8; ++j) {
    const int i = lane + 64 * j;
    const float wj = __builtin_amdgcn_rcpf(fmaf(t, R[j], 1.0f));
    float o = h[j] * (s * (kA * wj) + (1.0f - s));
    if (i >= 500) o = 0.0f;
    Or[i] = o;
  }
}

// Final [4096x512(pad)] @ [500x10] + b4. One wave per row, 4 rows per block.
__global__ __launch_bounds__(256) void gemm4_kernel(
    const float* __restrict__ Hm, const float* __restrict__ W,
    const float* __restrict__ b, float* __restrict__ out)
{
  const int w    = threadIdx.x >> 6;
  const int lane = threadIdx.x & 63;
  const int row  = blockIdx.x * 4 + w;
  float acc[10];
  #pragma unroll
  for (int o = 0; o < 10; ++o) acc[o] = 0.0f;

  const float* Hr = Hm + (size_t)row * 512;
  #pragma unroll
  for (int j = 0; j < 8; ++j) {
    const int kidx = lane + 64 * j;
    if (kidx < 500) {
      const float hv = Hr[kidx];
      const float* Wr = W + (size_t)kidx * 10;
      #pragma unroll
      for (int o = 0; o < 10; ++o) acc[o] = fmaf(hv, Wr[o], acc[o]);
    }
  }
  #pragma unroll
  for (int o = 0; o < 10; ++o) {
    #pragma unroll
    for (int off = 32; off; off >>= 1) acc[o] += __shfl_xor(acc[o], off);
  }
  if (lane == 0) {
    #pragma unroll
    for (int o = 0; o < 10; ++o) out[(size_t)row * 10 + o] = acc[o] + b[o];
  }
}

extern "C" void kernel_launch(void* const* d_in, const int* in_sizes, int n_in,
                              void* d_out, int out_size, void* d_ws, size_t ws_size,
                              hipStream_t stream)
{
  const float* x  = (const float*)d_in[0];
  const float* W1 = (const float*)d_in[1];
  const float* b1 = (const float*)d_in[2];
  const float* W2 = (const float*)d_in[3];
  const float* b2 = (const float*)d_in[4];
  const float* W3 = (const float*)d_in[5];
  const float* b3 = (const float*)d_in[6];
  const float* W4 = (const float*)d_in[7];
  const float* b4 = (const float*)d_in[8];
  const int* sparse = (const int*)d_in[9];

  float* out = (float*)d_out;
  char* ws = (char*)d_ws;

  unsigned int* cmax = (unsigned int*)ws;                      // 3 slots
  float* W1p = (float*)(ws + 256);                             // 1024x512
  float* W2p = W1p + (size_t)1024 * 512;                       // 512x512
  float* W3p = W2p + (size_t)512 * 512;                        // 512x512
  float* H   = W3p + (size_t)512 * 512;                        // 4096x512
  float* Hm  = H   + (size_t)4096 * 512;                       // 4096x512

  const dim3 gg(8, 64), gb(256);

  init_kernel<<<1, 64, 0, stream>>>(cmax);
  pad_w_kernel<<<2048, 256, 0, stream>>>(W1, W1p, 1024, 1024);
  pad_w_kernel<<<1024, 256, 0, stream>>>(W2, W2p, 500, 512);
  pad_w_kernel<<<1024, 256, 0, stream>>>(W3, W3p, 500, 512);

  // layer 1
  gemm_fused<<<gg, gb, 0, stream>>>(x, 1024, 1024, W1p, b1, H, cmax + 0);
  sinkhorn_kernel<<<1024, 256, 0, stream>>>(H, Hm, cmax + 0, sparse);

  // layer 2
  gemm_fused<<<gg, gb, 0, stream>>>(Hm, 512, 512, W2p, b2, H, cmax + 1);
  sinkhorn_kernel<<<1024, 256, 0, stream>>>(H, Hm, cmax + 1, sparse);

  // layer 3
  gemm_fused<<<gg, gb, 0, stream>>>(Hm, 512, 512, W3p, b3, H, cmax + 2);
  sinkhorn_kernel<<<1024, 256, 0, stream>>>(H, Hm, cmax + 2, sparse);

  // output layer
  gemm4_kernel<<<1024, 256, 0, stream>>>(Hm, W4, b4, out);
}

// Round 3
// 256.345 us; speedup vs baseline: 3.0651x; 3.0651x over previous
//
#include <hip/hip_runtime.h>
#include <math.h>

// ---------------------------------------------------------------------------
// NeuralNet_62045097558546 on MI355X (gfx950)
// 3x (GEMM+bias+ReLU+cmax -> soft-topk mask) -> GEMM+bias
// GEMMs run on bf16 MFMA with split precision: C = Ahi*Bhi + Ahi*Blo + Alo*Bhi
// as ONE bf16 GEMM over K' = 3K:  A' = [hi | hi | lo] (stored compact [hi|lo],
// segment remap in staging), B' = [hi ; lo ; hi] (materialized, transposed).
// ---------------------------------------------------------------------------

typedef __attribute__((ext_vector_type(8))) short short8;
typedef __attribute__((ext_vector_type(4))) float f32x4;

__device__ __forceinline__ unsigned short f2bf(float f) {
  unsigned u = __float_as_uint(f);
  u += 0x7fffu + ((u >> 16) & 1u);
  return (unsigned short)(u >> 16);
}
__device__ __forceinline__ float bf2f(unsigned short s) {
  return __uint_as_float(((unsigned)s) << 16);
}

// ---------------------------------------------------------------------------
// MFMA GEMM: H[4096][512] = relu(A*B + bias), fused global cmax of
// max(h^2,(h-1)^2) over real cols (<500).
// A2: [4096][2K] bf16  ([hi(K) | lo(K)])
// B3: [512][3K] bf16   (transposed weights, [hi | lo | hi] along k')
// Block: 256 thr = 4 waves (2x2), wave tile 32x32 = 2x2 MFMA 16x16x32.
// Block tile 64x64, grid (8, 64) = 512 blocks. LDS 16 KB double-buffered.
// Frag k-window: lane l holds k = (l>>4)*8 .. +7 for BOTH A and B (any HW
// k-mapping gives the correct dot product as long as A/B agree).
// ---------------------------------------------------------------------------
__global__ __launch_bounds__(256, 2) void gemm_mfma(
    const short* __restrict__ A2, const short* __restrict__ B3, int K,
    const float* __restrict__ bp, float* __restrict__ H,
    unsigned int* __restrict__ cmax)
{
  __shared__ __align__(16) short lds[8192];   // [2 buf][A:2048 | B:2048]
  const int tid  = threadIdx.x;
  const int lane = tid & 63, w = tid >> 6;
  const int wr = w >> 1, wc = w & 1;
  const int row0 = blockIdx.y * 64, col0 = blockIdx.x * 64;

  // ---- staging mapping: thread -> (row-in-tile sm, k-group sg) ----
  const int sm = tid >> 2, sg = tid & 3;
  const int pos = sg * 64 + ((sm + 4 * sg) & 63);   // conflict-free chunk slot
  const short* ArowB = A2 + (size_t)(row0 + sm) * (2 * K);
  const short* BrowB = B3 + (size_t)(col0 + sm) * (3 * K);
  const int sgo = sg * 8;

  // ---- fragment read chunks (lane l: group rg = l>>4, 16-row tiles) ----
  const int rg = lane >> 4, rl = lane & 15;
  const int mm0 = wr * 32 + rl,      mm1 = mm0 + 16;
  const int nn0 = wc * 32 + rl,      nn1 = nn0 + 16;
  const int ca0 = rg * 64 + ((mm0 + 4 * rg) & 63);
  const int ca1 = rg * 64 + ((mm1 + 4 * rg) & 63);
  const int cb0 = rg * 64 + ((nn0 + 4 * rg) & 63);
  const int cb1 = rg * 64 + ((nn1 + 4 * rg) & 63);

  const f32x4 zero = {0.f, 0.f, 0.f, 0.f};
  f32x4 acc00 = zero, acc01 = zero, acc10 = zero, acc11 = zero;
  const int NT = (3 * K) >> 5;

  // ---- prologue: stage tile 0 ----
  {
    const int kk = sgo;
    const int as = (kk >= K) ? kk - K : kk;
    uint4 aR = *(const uint4*)(ArowB + as);
    uint4 bR = *(const uint4*)(BrowB + kk);
    *(uint4*)&lds[pos * 8]        = aR;
    *(uint4*)&lds[2048 + pos * 8] = bR;
  }
  __syncthreads();

  int cur = 0;
  for (int kt = 0; kt < NT; ++kt) {
    const bool pre = (kt + 1 < NT);
    uint4 aN, bN;
    if (pre) {
      const int kk = (kt + 1) * 32 + sgo;
      const int as = (kk >= K) ? kk - K : kk;
      aN = *(const uint4*)(ArowB + as);
      bN = *(const uint4*)(BrowB + kk);
    }
    const short* L = lds + cur * 4096;
    const short8 a0 = *(const short8*)&L[ca0 * 8];
    const short8 a1 = *(const short8*)&L[ca1 * 8];
    const short8 b0 = *(const short8*)&L[2048 + cb0 * 8];
    const short8 b1 = *(const short8*)&L[2048 + cb1 * 8];
    acc00 = __builtin_amdgcn_mfma_f32_16x16x32_bf16(a0, b0, acc00, 0, 0, 0);
    acc01 = __builtin_amdgcn_mfma_f32_16x16x32_bf16(a0, b1, acc01, 0, 0, 0);
    acc10 = __builtin_amdgcn_mfma_f32_16x16x32_bf16(a1, b0, acc10, 0, 0, 0);
    acc11 = __builtin_amdgcn_mfma_f32_16x16x32_bf16(a1, b1, acc11, 0, 0, 0);
    if (pre) {
      short* Lw = lds + (cur ^ 1) * 4096;
      *(uint4*)&Lw[pos * 8]        = aN;
      *(uint4*)&Lw[2048 + pos * 8] = bN;
    }
    __syncthreads();
    cur ^= 1;
  }

  // ---- epilogue: bias + relu + store + cmax ----
  float localmax = 0.0f;
  const f32x4* accs[4] = {&acc00, &acc01, &acc10, &acc11};
  #pragma unroll
  for (int ti = 0; ti < 2; ++ti) {
    #pragma unroll
    for (int tj = 0; tj < 2; ++tj) {
      const f32x4 a = *accs[ti * 2 + tj];
      const int col = col0 + wc * 32 + tj * 16 + rl;
      const float bb = bp[col];
      const int rbase = row0 + wr * 32 + ti * 16 + rg * 4;
      #pragma unroll
      for (int i = 0; i < 4; ++i) {
        float v = a[i] + bb;
        v = fmaxf(v, 0.0f);
        H[(size_t)(rbase + i) * 512 + col] = v;
        if (col < 500) {
          const float vm = v - 1.0f;
          localmax = fmaxf(localmax, fmaxf(v * v, vm * vm));
        }
      }
    }
  }
  #pragma unroll
  for (int off = 32; off; off >>= 1)
    localmax = fmaxf(localmax, __shfl_xor(localmax, off));
  if (lane == 0) atomicMax(cmax, __float_as_uint(localmax));
}

// Zero the three cmax accumulator slots (re-init every call: replay-safe).
__global__ void init_kernel(unsigned int* c)
{
  if (threadIdx.x < 3) c[threadIdx.x] = 0u;
}

// Pad biases into bp[3][512] (pad cols = 0).
__global__ __launch_bounds__(256) void pad_bias_kernel(
    const float* __restrict__ b1, const float* __restrict__ b2,
    const float* __restrict__ b3, float* __restrict__ bp)
{
  const int idx = blockIdx.x * 256 + threadIdx.x;
  if (idx < 1536) {
    const int L = idx >> 9, c = idx & 511;
    const float* src = (L == 0) ? b1 : (L == 1) ? b2 : b3;
    bp[idx] = (c < 500) ? src[c] : 0.0f;
  }
}

// x[4096][1024] f32 -> X2[4096][2048] bf16 ([hi|lo]).
__global__ __launch_bounds__(256) void convert_x_kernel(
    const float* __restrict__ x, short* __restrict__ X2)
{
  const int idx = blockIdx.x * 256 + threadIdx.x;   // 4096*1024 threads
  const int r = idx >> 10, k = idx & 1023;
  const float v = x[idx];
  const unsigned short hi = f2bf(v);
  const unsigned short lo = f2bf(v - bf2f(hi));
  short* o = X2 + (size_t)r * 2048;
  o[k] = (short)hi;
  o[1024 + k] = (short)lo;
}

// W1[1024][500] f32 -> B3T1[512][3072] bf16 (transposed, [hi|lo|hi]).
__global__ __launch_bounds__(256) void convert_w1_kernel(
    const float* __restrict__ W, short* __restrict__ B3T)
{
  const int idx = blockIdx.x * 256 + threadIdx.x;   // 512*1024 threads
  const int n = idx >> 10, k = idx & 1023;
  const float v = (n < 500) ? W[k * 500 + n] : 0.0f;
  const unsigned short hi = f2bf(v);
  const unsigned short lo = f2bf(v - bf2f(hi));
  short* o = B3T + (size_t)n * 3072;
  o[k] = (short)hi;
  o[1024 + k] = (short)lo;
  o[2048 + k] = (short)hi;
}

// W[500][500] f32 -> B3T[512][1536] bf16 (transposed, [hi|lo|hi], zero pad).
__global__ __launch_bounds__(256) void convert_w2_kernel(
    const float* __restrict__ W, short* __restrict__ B3T)
{
  const int idx = blockIdx.x * 256 + threadIdx.x;   // 512*512 threads
  const int n = idx >> 9, k = idx & 511;
  const float v = (n < 500 && k < 500) ? W[k * 500 + n] : 0.0f;
  const unsigned short hi = f2bf(v);
  const unsigned short lo = f2bf(v - bf2f(hi));
  short* o = B3T + (size_t)n * 1536;
  o[k] = (short)hi;
  o[512 + k] = (short)lo;
  o[1024 + k] = (short)hi;
}

// Soft top-k (2-anchor Sinkhorn collapsed to scalar fixed point), writes the
// masked activations as bf16 [hi(512)|lo(512)] rows for the next MFMA GEMM.
__global__ __launch_bounds__(256) void sinkhorn_kernel(
    const float* __restrict__ H, short* __restrict__ Out2,
    const unsigned int* __restrict__ cmaxp, const int* __restrict__ sparse)
{
  const int w    = threadIdx.x >> 6;
  const int lane = threadIdx.x & 63;
  const int row  = blockIdx.x * 4 + w;
  const float cmax = __uint_as_float(cmaxp[0]);
  const float s    = (float)sparse[0];
  const float inv  = 1.0f / (0.1f * cmax);

  const float* Hr = H + (size_t)row * 512;
  float h[8], R[8];
  #pragma unroll
  for (int j = 0; j < 8; ++j) {
    h[j] = Hr[lane + 64 * j];                 // pad cols are 0
    R[j] = __expf((2.0f * h[j] - 1.0f) * inv);
  }
  const bool v7 = (lane < 52);                // lane+448 < 500

  float t = 1.0f, A = 0.0f;
  for (int it = 0; it < 50; ++it) {
    A = 0.0f;
    #pragma unroll
    for (int j = 0; j < 8; ++j) {
      float wj = __builtin_amdgcn_rcpf(fmaf(t, R[j], 1.0f));
      if (j == 7 && !v7) wj = 0.0f;
      A += wj;
    }
    #pragma unroll
    for (int off = 32; off; off >>= 1) A += __shfl_xor(A, off);
    if (it < 49) t = 0.25f * A * t * __builtin_amdgcn_rcpf(500.0f - A);
  }

  const float kA = 400.0f / A;
  short* Or = Out2 + (size_t)row * 1024;
  #pragma unroll
  for (int j = 0; j < 8; ++j) {
    const int i = lane + 64 * j;
    const float wj = __builtin_amdgcn_rcpf(fmaf(t, R[j], 1.0f));
    float o = h[j] * (s * (kA * wj) + (1.0f - s));
    if (i >= 500) o = 0.0f;
    const unsigned short hi = f2bf(o);
    const unsigned short lo = f2bf(o - bf2f(hi));
    Or[i] = (short)hi;
    Or[512 + i] = (short)lo;
  }
}

// Final [4096x500] @ [500x10] + b4 from bf16 hi/lo rows. One wave per row.
__global__ __launch_bounds__(256) void gemm4_kernel(
    const short* __restrict__ Hm2, const float* __restrict__ W,
    const float* __restrict__ b, float* __restrict__ out)
{
  const int w    = threadIdx.x >> 6;
  const int lane = threadIdx.x & 63;
  const int row  = blockIdx.x * 4 + w;
  float acc[10];
  #pragma unroll
  for (int o = 0; o < 10; ++o) acc[o] = 0.0f;

  const short* Hr = Hm2 + (size_t)row * 1024;
  #pragma unroll
  for (int j = 0; j < 8; ++j) {
    const int kidx = lane + 64 * j;
    if (kidx < 500) {
      const float hv = bf2f((unsigned short)Hr[kidx]) +
                       bf2f((unsigned short)Hr[512 + kidx]);
      const float* Wr = W + (size_t)kidx * 10;
      #pragma unroll
      for (int o = 0; o < 10; ++o) acc[o] = fmaf(hv, Wr[o], acc[o]);
    }
  }
  #pragma unroll
  for (int o = 0; o < 10; ++o) {
    #pragma unroll
    for (int off = 32; off; off >>= 1) acc[o] += __shfl_xor(acc[o], off);
  }
  if (lane == 0) {
    #pragma unroll
    for (int o = 0; o < 10; ++o) out[(size_t)row * 10 + o] = acc[o] + b[o];
  }
}

extern "C" void kernel_launch(void* const* d_in, const int* in_sizes, int n_in,
                              void* d_out, int out_size, void* d_ws, size_t ws_size,
                              hipStream_t stream)
{
  const float* x  = (const float*)d_in[0];
  const float* W1 = (const float*)d_in[1];
  const float* b1 = (const float*)d_in[2];
  const float* W2 = (const float*)d_in[3];
  const float* b2 = (const float*)d_in[4];
  const float* W3 = (const float*)d_in[5];
  const float* b3 = (const float*)d_in[6];
  const float* W4 = (const float*)d_in[7];
  const float* b4 = (const float*)d_in[8];
  const int* sparse = (const int*)d_in[9];

  float* out = (float*)d_out;
  char* ws = (char*)d_ws;

  // workspace layout (256-aligned)
  unsigned int* cmax = (unsigned int*)ws;                        // 3 slots
  float* bp   = (float*)(ws + 256);                              // [3][512]
  short* X2   = (short*)(ws + 8192);                             // 4096x2048
  short* B3T1 = X2 + (size_t)4096 * 2048;                        // 512x3072
  short* B3T2 = B3T1 + (size_t)512 * 3072;                       // 512x1536
  short* B3T3 = B3T2 + (size_t)512 * 1536;                       // 512x1536
  float* H    = (float*)(B3T3 + (size_t)512 * 1536);             // 4096x512
  short* Hm2  = (short*)(H + (size_t)4096 * 512);                // 4096x1024

  const dim3 gg(8, 64), gb(256);

  init_kernel<<<1, 64, 0, stream>>>(cmax);
  pad_bias_kernel<<<6, 256, 0, stream>>>(b1, b2, b3, bp);
  convert_x_kernel<<<16384, 256, 0, stream>>>(x, X2);
  convert_w1_kernel<<<2048, 256, 0, stream>>>(W1, B3T1);
  convert_w2_kernel<<<1024, 256, 0, stream>>>(W2, B3T2);
  convert_w2_kernel<<<1024, 256, 0, stream>>>(W3, B3T3);

  // layer 1
  gemm_mfma<<<gg, gb, 0, stream>>>(X2, B3T1, 1024, bp, H, cmax + 0);
  sinkhorn_kernel<<<1024, 256, 0, stream>>>(H, Hm2, cmax + 0, sparse);

  // layer 2
  gemm_mfma<<<gg, gb, 0, stream>>>(Hm2, B3T2, 512, bp + 512, H, cmax + 1);
  sinkhorn_kernel<<<1024, 256, 0, stream>>>(H, Hm2, cmax + 1, sparse);

  // layer 3
  gemm_mfma<<<gg, gb, 0, stream>>>(Hm2, B3T3, 512, bp + 1024, H, cmax + 2);
  sinkhorn_kernel<<<1024, 256, 0, stream>>>(H, Hm2, cmax + 2, sparse);

  // output layer
  gemm4_kernel<<<1024, 256, 0, stream>>>(Hm2, W4, b4, out);
}

// Round 5
// 216.365 us; speedup vs baseline: 3.6314x; 1.1848x over previous
//
#include <hip/hip_runtime.h>
#include <math.h>

// ---------------------------------------------------------------------------
// NeuralNet_62045097558546 on MI355X (gfx950)
// 3x (GEMM+bias+ReLU+cmax -> soft-topk mask) -> GEMM+bias
// GEMMs: bf16 MFMA split precision, C = Ahi*Bhi + Ahi*Blo + Alo*Bhi as one
// bf16 GEMM over K' = 3K. Physical storage is compact [hi(K) | lo(K)] tiles;
// logical tile t remaps: A (=[hi|hi|lo]): ta = t<NTK ? t : t-NTK
//                        B (=[hi|lo|hi]): tb = t<2NTK ? t : t-2NTK
//
// BLOCKED OPERAND LAYOUT (built by prep/sinkhorn, consumed by gemm):
//   panel p (64 rows) -> tile t (32 k') -> slot s (0..255) of 8 shorts
//   slot s holds chunk (m = s>>2, g = (s&3) ^ ((s>>3)&3))   [XOR bank swizzle]
//   = element rows 64p+m, k' = 32t + 8g .. +7
// GEMM staging is then a PURE LINEAR copy (4x global_load_lds of 1KB), fully
// coalesced; ds_read_b128 in compute is 2-way bank-aliased (free).
//
// GEMM: 512 blocks x 4 waves, per-wave split-K over private double-buffered
// 16KB LDS -> zero barriers in K-loop, counted s_waitcnt vmcnt(8).
// Epilogue: LDS split-K reduce + bias + relu + fused global cmax.
// ---------------------------------------------------------------------------

typedef __attribute__((ext_vector_type(8))) short short8;
typedef __attribute__((ext_vector_type(4))) float f32x4;

__device__ __forceinline__ unsigned short f2bf(float f) {
  unsigned u = __float_as_uint(f);
  u += 0x7fffu + ((u >> 16) & 1u);
  return (unsigned short)(u >> 16);
}
__device__ __forceinline__ float bf2f(unsigned short s) {
  return __uint_as_float(((unsigned)s) << 16);
}

__device__ __forceinline__ void gload16(const void* g, void* l) {
  __builtin_amdgcn_global_load_lds(
      (const __attribute__((address_space(1))) void*)g,
      (__attribute__((address_space(3))) void*)l, 16, 0, 0);
}

// NTK = K/32 (number of 32-wide hi tiles). Blocked panel = 2*NTK tiles.
__global__ __launch_bounds__(256, 2) void gemm_mfma(
    const short* __restrict__ Ablk, const short* __restrict__ Bblk,
    const int NTK,
    const float* __restrict__ bp, float* __restrict__ H,
    unsigned int* __restrict__ cmax)
{
  __shared__ __align__(16) short lds[32768];   // 64KB = 4 waves x 16KB

  const int tid  = threadIdx.x;
  const int lane = tid & 63, w = tid >> 6;
  const int rg = lane >> 4, rl = lane & 15;

  // by = row-panel (fast), bx = col-panel: XCD (blockIdx%8) sees rows==XCD
  // mod 8 for every col pass -> 2MB of A per XCD stays L2-resident.
  const int by = blockIdx.x & 63, bx = blockIdx.x >> 6;
  const int row0 = by * 64, col0 = bx * 64;

  const size_t Apanel = (size_t)by * (2 * NTK) * 2048;
  const size_t Bpanel = (size_t)bx * (2 * NTK) * 2048;

  short* ldsW = lds + w * 8192;    // private 16KB (2 buf x 8KB)

  const int nt = (3 * NTK) >> 2;   // logical tiles per wave (24 / 12)
  const int tb0 = w * nt;

  auto stage = [&](int buf, int t) {
    const int ta = (t < NTK) ? t : t - NTK;          // A' = [hi|hi|lo]
    const int tbb = (t < 2 * NTK) ? t : t - 2 * NTK; // B' = [hi|lo|hi]
    const short* Ag = Ablk + Apanel + (size_t)ta * 2048 + lane * 8;
    const short* Bg = Bblk + Bpanel + (size_t)tbb * 2048 + lane * 8;
    short* Ab = ldsW + buf * 4096;
    short* Bb = Ab + 2048;
    #pragma unroll
    for (int j = 0; j < 4; ++j)
      gload16(Ag + j * 512, Ab + j * 512);
    #pragma unroll
    for (int j = 0; j < 4; ++j)
      gload16(Bg + j * 512, Bb + j * 512);
  };

  f32x4 acc[4][4];
  #pragma unroll
  for (int s = 0; s < 4; ++s)
    #pragma unroll
    for (int u = 0; u < 4; ++u)
      acc[s][u] = (f32x4){0.f, 0.f, 0.f, 0.f};

  // slot for (m = s*16+rl, g = rg): (s*16+rl)*4 + (rg ^ ((rl>>1)&3))
  const int swz = rg ^ ((rl >> 1) & 3);

  auto compute = [&](int cur) {
    const short* L = ldsW + cur * 4096;
    short8 af[4], bq[4];
    #pragma unroll
    for (int s = 0; s < 4; ++s)
      af[s] = *(const short8*)&L[((s * 16 + rl) * 4 + swz) * 8];
    #pragma unroll
    for (int s = 0; s < 4; ++s)
      bq[s] = *(const short8*)&L[2048 + ((s * 16 + rl) * 4 + swz) * 8];
    #pragma unroll
    for (int s = 0; s < 4; ++s)
      #pragma unroll
      for (int u = 0; u < 4; ++u)
        acc[s][u] = __builtin_amdgcn_mfma_f32_16x16x32_bf16(af[s], bq[u], acc[s][u], 0, 0, 0);
  };

  stage(0, tb0);
  for (int t = 0; t + 1 < nt; ++t) {
    stage((t & 1) ^ 1, tb0 + t + 1);
    __builtin_amdgcn_sched_barrier(0);
    asm volatile("s_waitcnt vmcnt(8)" ::: "memory");   // cur buffer ready
    __builtin_amdgcn_sched_barrier(0);
    compute(t & 1);
  }
  asm volatile("s_waitcnt vmcnt(0)" ::: "memory");
  __builtin_amdgcn_sched_barrier(0);
  compute((nt - 1) & 1);

  // ---- epilogue: 2-pass cross-wave split-K reduce + bias + relu + cmax ----
  float* fl = (float*)lds;             // 4 regions x [32][68] f32
  float lmax = 0.0f;
  __syncthreads();                     // all waves done with staging LDS

  #pragma unroll
  for (int p = 0; p < 2; ++p) {
    #pragma unroll
    for (int sp = 0; sp < 2; ++sp) {
      const int s = p * 2 + sp;
      #pragma unroll
      for (int u = 0; u < 4; ++u)
        #pragma unroll
        for (int i = 0; i < 4; ++i)
          fl[w * 2176 + (sp * 16 + rg * 4 + i) * 68 + u * 16 + rl] = acc[s][u][i];
    }
    __syncthreads();

    const int rloc = w * 8 + (lane >> 3);      // 0..31
    const int c0 = (lane & 7) * 8;
    f32x4 s0 = {0.f, 0.f, 0.f, 0.f}, s1 = {0.f, 0.f, 0.f, 0.f};
    #pragma unroll
    for (int q = 0; q < 4; ++q) {
      const float* src = fl + q * 2176 + rloc * 68 + c0;
      s0 += *(const f32x4*)src;
      s1 += *(const f32x4*)(src + 4);
    }
    const int gr = row0 + p * 32 + rloc;
    const int gc = col0 + c0;
    const f32x4 bb0 = *(const f32x4*)&bp[gc];
    const f32x4 bb1 = *(const f32x4*)&bp[gc + 4];
    f32x4 o0, o1;
    #pragma unroll
    for (int i = 0; i < 4; ++i) {
      o0[i] = fmaxf(s0[i] + bb0[i], 0.f);
      o1[i] = fmaxf(s1[i] + bb1[i], 0.f);
    }
    float* Hp = H + (size_t)gr * 512 + gc;
    *(f32x4*)Hp = o0;
    *(f32x4*)(Hp + 4) = o1;
    #pragma unroll
    for (int i = 0; i < 4; ++i) {
      if (gc + i < 500) {
        const float v = o0[i], vm = v - 1.0f;
        lmax = fmaxf(lmax, fmaxf(v * v, vm * vm));
      }
      if (gc + 4 + i < 500) {
        const float v = o1[i], vm = v - 1.0f;
        lmax = fmaxf(lmax, fmaxf(v * v, vm * vm));
      }
    }
    if (p == 0) __syncthreads();
  }

  #pragma unroll
  for (int off = 32; off; off >>= 1)
    lmax = fmaxf(lmax, __shfl_xor(lmax, off));
  if (lane == 0) atomicMax(cmax, __float_as_uint(lmax));
}

// ---------------------------------------------------------------------------
// Fused prep: x -> Ablk (hi/lo blocked), W1/W2/W3 -> blocked transposed
// [hi|lo], bias pad, cmax init. Work items:
//   A : 4096*128 = 524288   (row, kc)  K=1024
//   W1:  512*128 =  65536   (n, kc)    K=1024
//   W2:  512* 64 =  32768   (n, kc)    K=512
//   W3:  512* 64 =  32768
//   bias 1536, cmax 3      TOTAL 656899 -> grid 2567
// ---------------------------------------------------------------------------
__device__ __forceinline__ void blk_write(
    short* __restrict__ dst, int panel, int NTK2 /*=2*NTK*/,
    int m, int kc, const float* v)
{
  const int t = kc >> 2, g = kc & 3;
  const int slot = m * 4 + (g ^ ((m >> 1) & 3));
  short* o = dst + ((size_t)panel * NTK2 + t) * 2048 + slot * 8;
  short hi[8], lo[8];
  #pragma unroll
  for (int i = 0; i < 8; ++i) {
    const unsigned short h = f2bf(v[i]);
    hi[i] = (short)h;
    lo[i] = (short)f2bf(v[i] - bf2f(h));
  }
  *(uint4*)o = *(const uint4*)hi;
  *(uint4*)(o + (size_t)(NTK2 >> 1) * 2048) = *(const uint4*)lo;
}

__global__ __launch_bounds__(256) void prep_kernel(
    const float* __restrict__ x,  short* __restrict__ Ablk,
    const float* __restrict__ W1, short* __restrict__ B1blk,
    const float* __restrict__ W2, short* __restrict__ B2blk,
    const float* __restrict__ W3, short* __restrict__ B3blk,
    const float* __restrict__ b1, const float* __restrict__ b2,
    const float* __restrict__ b3, float* __restrict__ bp,
    unsigned int* __restrict__ cmax)
{
  int idx = blockIdx.x * 256 + threadIdx.x;
  if (idx < 524288) {                        // x -> Ablk
    const int row = idx >> 7, kc = idx & 127;
    float v[8];
    #pragma unroll
    for (int i = 0; i < 8; ++i) v[i] = x[(size_t)row * 1024 + kc * 8 + i];
    blk_write(Ablk, row >> 6, 64, row & 63, kc, v);
    return;
  }
  idx -= 524288;
  if (idx < 65536) {                         // W1 -> B1blk
    const int n = idx >> 7, kc = idx & 127;
    float v[8];
    #pragma unroll
    for (int i = 0; i < 8; ++i)
      v[i] = (n < 500) ? W1[(size_t)(kc * 8 + i) * 500 + n] : 0.0f;
    blk_write(B1blk, n >> 6, 64, n & 63, kc, v);
    return;
  }
  idx -= 65536;
  if (idx < 32768) {                         // W2 -> B2blk
    const int n = idx >> 6, kc = idx & 63;
    float v[8];
    #pragma unroll
    for (int i = 0; i < 8; ++i) {
      const int k = kc * 8 + i;
      v[i] = (n < 500 && k < 500) ? W2[(size_t)k * 500 + n] : 0.0f;
    }
    blk_write(B2blk, n >> 6, 32, n & 63, kc, v);
    return;
  }
  idx -= 32768;
  if (idx < 32768) {                         // W3 -> B3blk
    const int n = idx >> 6, kc = idx & 63;
    float v[8];
    #pragma unroll
    for (int i = 0; i < 8; ++i) {
      const int k = kc * 8 + i;
      v[i] = (n < 500 && k < 500) ? W3[(size_t)k * 500 + n] : 0.0f;
    }
    blk_write(B3blk, n >> 6, 32, n & 63, kc, v);
    return;
  }
  idx -= 32768;
  if (idx < 1536) {                          // bias pad bp[3][512]
    const int L = idx >> 9, c = idx & 511;
    const float* src = (L == 0) ? b1 : (L == 1) ? b2 : b3;
    bp[idx] = (c < 500) ? src[c] : 0.0f;
    return;
  }
  idx -= 1536;
  if (idx < 3) cmax[idx] = 0u;               // cmax init (replay-safe)
}

// ---------------------------------------------------------------------------
// Soft top-k (2-anchor Sinkhorn collapsed to scalar fixed point). One wave
// per row; lane l owns contiguous k = 8l..8l+7. Writes masked activations
// directly in blocked hi/lo layout (panel=row>>6, NTK=16).
// ---------------------------------------------------------------------------
__global__ __launch_bounds__(256) void sinkhorn_kernel(
    const float* __restrict__ H, short* __restrict__ Outblk,
    const unsigned int* __restrict__ cmaxp, const int* __restrict__ sparse)
{
  const int w    = threadIdx.x >> 6;
  const int lane = threadIdx.x & 63;
  const int row  = blockIdx.x * 4 + w;
  const float cmax = __uint_as_float(cmaxp[0]);
  const float s    = (float)sparse[0];
  const float inv  = 1.0f / (0.1f * cmax);

  const float* Hr = H + (size_t)row * 512 + lane * 8;
  const f32x4 h0 = *(const f32x4*)Hr;
  const f32x4 h1 = *(const f32x4*)(Hr + 4);
  float h[8] = {h0[0], h0[1], h0[2], h0[3], h1[0], h1[1], h1[2], h1[3]};
  float R[8];
  #pragma unroll
  for (int j = 0; j < 8; ++j) R[j] = __expf((2.0f * h[j] - 1.0f) * inv);

  const int nval = min(max(500 - lane * 8, 0), 8);   // valid k this lane

  float t = 1.0f, A = 0.0f;
  for (int it = 0; it < 50; ++it) {
    A = 0.0f;
    #pragma unroll
    for (int j = 0; j < 8; ++j) {
      float wj = __builtin_amdgcn_rcpf(fmaf(t, R[j], 1.0f));
      if (j >= nval) wj = 0.0f;
      A += wj;
    }
    #pragma unroll
    for (int off = 32; off; off >>= 1) A += __shfl_xor(A, off);
    if (it < 49) t = 0.25f * A * t * __builtin_amdgcn_rcpf(500.0f - A);
  }

  const float kA = 400.0f / A;
  short hi[8], lo[8];
  #pragma unroll
  for (int j = 0; j < 8; ++j) {
    const float wj = __builtin_amdgcn_rcpf(fmaf(t, R[j], 1.0f));
    float o = h[j] * (s * (kA * wj) + (1.0f - s));
    if (j >= nval) o = 0.0f;
    const unsigned short hh = f2bf(o);
    hi[j] = (short)hh;
    lo[j] = (short)f2bf(o - bf2f(hh));
  }
  const int p = row >> 6, m = row & 63;
  const int tt = lane >> 2;
  const int slot = m * 4 + ((lane & 3) ^ ((m >> 1) & 3));
  short* o = Outblk + ((size_t)p * 32 + tt) * 2048 + slot * 8;
  *(uint4*)o           = *(const uint4*)hi;
  *(uint4*)(o + 32768) = *(const uint4*)lo;   // lo tiles: +NTK(16)*2048
}

// Final [4096x500] @ [500x10] + b4 from blocked hi/lo rows. 1 wave per row.
__global__ __launch_bounds__(256) void gemm4_kernel(
    const short* __restrict__ Hblk, const float* __restrict__ W,
    const float* __restrict__ b, float* __restrict__ out)
{
  const int w    = threadIdx.x >> 6;
  const int lane = threadIdx.x & 63;
  const int row  = blockIdx.x * 4 + w;

  const int p = row >> 6, m = row & 63;
  const int tt = lane >> 2;
  const int slot = m * 4 + ((lane & 3) ^ ((m >> 1) & 3));
  const short* src = Hblk + ((size_t)p * 32 + tt) * 2048 + slot * 8;
  const uint4 hv4 = *(const uint4*)src;
  const uint4 lv4 = *(const uint4*)(src + 32768);
  const short* hs = (const short*)&hv4;
  const short* ls = (const short*)&lv4;

  const int nval = min(max(500 - lane * 8, 0), 8);
  float acc[10];
  #pragma unroll
  for (int o = 0; o < 10; ++o) acc[o] = 0.0f;

  #pragma unroll
  for (int i = 0; i < 8; ++i) {
    if (i < nval) {
      const float hvv = bf2f((unsigned short)hs[i]) + bf2f((unsigned short)ls[i]);
      const float* Wr = W + (size_t)(lane * 8 + i) * 10;
      #pragma unroll
      for (int o = 0; o < 10; ++o) acc[o] = fmaf(hvv, Wr[o], acc[o]);
    }
  }
  #pragma unroll
  for (int o = 0; o < 10; ++o) {
    #pragma unroll
    for (int off = 32; off; off >>= 1) acc[o] += __shfl_xor(acc[o], off);
  }
  if (lane == 0) {
    #pragma unroll
    for (int o = 0; o < 10; ++o) out[(size_t)row * 10 + o] = acc[o] + b[o];
  }
}

extern "C" void kernel_launch(void* const* d_in, const int* in_sizes, int n_in,
                              void* d_out, int out_size, void* d_ws, size_t ws_size,
                              hipStream_t stream)
{
  const float* x  = (const float*)d_in[0];
  const float* W1 = (const float*)d_in[1];
  const float* b1 = (const float*)d_in[2];
  const float* W2 = (const float*)d_in[3];
  const float* b2 = (const float*)d_in[4];
  const float* W3 = (const float*)d_in[5];
  const float* b3 = (const float*)d_in[6];
  const float* W4 = (const float*)d_in[7];
  const float* b4 = (const float*)d_in[8];
  const int* sparse = (const int*)d_in[9];

  float* out = (float*)d_out;
  char* ws = (char*)d_ws;

  unsigned int* cmax = (unsigned int*)ws;                        // 3 slots
  float* bp    = (float*)(ws + 256);                             // [3][512]
  short* Ablk  = (short*)(ws + 8192);                            // 16MB
  short* B1blk = Ablk  + (size_t)64 * 64 * 2048;                 // 2MB
  short* B2blk = B1blk + (size_t)8 * 64 * 2048;                  // 1MB
  short* B3blk = B2blk + (size_t)8 * 32 * 2048;                  // 1MB
  float* H     = (float*)(B3blk + (size_t)8 * 32 * 2048);        // 8MB
  short* Hmblk = (short*)(H + (size_t)4096 * 512);               // 8MB

  prep_kernel<<<2567, 256, 0, stream>>>(x, Ablk, W1, B1blk, W2, B2blk,
                                        W3, B3blk, b1, b2, b3, bp, cmax);

  gemm_mfma<<<512, 256, 0, stream>>>(Ablk, B1blk, 32, bp, H, cmax + 0);
  sinkhorn_kernel<<<1024, 256, 0, stream>>>(H, Hmblk, cmax + 0, sparse);

  gemm_mfma<<<512, 256, 0, stream>>>(Hmblk, B2blk, 16, bp + 512, H, cmax + 1);
  sinkhorn_kernel<<<1024, 256, 0, stream>>>(H, Hmblk, cmax + 1, sparse);

  gemm_mfma<<<512, 256, 0, stream>>>(Hmblk, B3blk, 16, bp + 1024, H, cmax + 2);
  sinkhorn_kernel<<<1024, 256, 0, stream>>>(H, Hmblk, cmax + 2, sparse);

  gemm4_kernel<<<1024, 256, 0, stream>>>(Hmblk, W4, b4, out);
}

// Round 6
// 190.860 us; speedup vs baseline: 4.1167x; 1.1336x over previous
//
#include <hip/hip_runtime.h>
#include <math.h>

// ---------------------------------------------------------------------------
// NeuralNet_62045097558546 on MI355X (gfx950)
// 3x (GEMM+bias+ReLU+cmax -> soft-topk mask) -> GEMM+bias
// GEMMs: bf16 MFMA split precision, C = Ahi*Bhi + Ahi*Blo + Alo*Bhi as one
// bf16 GEMM over K' = 3K. Physical storage: compact [hi(NTK) | lo(NTK)] tiles.
// Logical tile t: A (=[hi|hi|lo]): ta = t<NTK ? t : t-NTK
//                B (=[hi|lo|hi]): tb = t<2NTK ? t : t-2NTK
//
// FRAGMENT-ORDER BLOCKED LAYOUT (built by prep/sinkhorn, read by gemm):
//   panel p (64 rows) -> tile t (32 k') -> slot s (0..255) of 8 shorts
//   slot s = (m>>4)*64 + g*16 + (m&15)  holds  (row m, k-chunk g)
//   => MFMA fragment load = 64 lanes read ONE CONTIGUOUS 1KB block
//      (lane l gets m = s16*16 + (l&15), g = l>>4  -- the A/B-agreeing
//       k-window convention, k-mapping-proof).
// K-loop: NO LDS. Fragments stream global(L2)->VGPR with a 3-deep register
// pipeline; per-wave split-K (4 waves = 4 k-quarters); LDS used only for the
// split-K epilogue reduce + bias + relu + fused global cmax.
// ---------------------------------------------------------------------------

typedef __attribute__((ext_vector_type(8))) short short8;
typedef __attribute__((ext_vector_type(4))) float f32x4;

__device__ __forceinline__ unsigned short f2bf(float f) {
  unsigned u = __float_as_uint(f);
  u += 0x7fffu + ((u >> 16) & 1u);
  return (unsigned short)(u >> 16);
}
__device__ __forceinline__ float bf2f(unsigned short s) {
  return __uint_as_float(((unsigned)s) << 16);
}

// NTK = K/32. Physical panel stride = 2*NTK tiles (hi+lo).
__global__ __launch_bounds__(256, 2) void gemm_mfma(
    const short* __restrict__ Ablk, const short* __restrict__ Bblk,
    const int NTK,
    const float* __restrict__ bp, float* __restrict__ H,
    unsigned int* __restrict__ cmax)
{
  __shared__ __align__(16) float fl[8704];   // epilogue only: 4 x [32][68]

  const int tid  = threadIdx.x;
  const int lane = tid & 63, w = tid >> 6;
  const int rg = lane >> 4, rl = lane & 15;

  // by = row-panel (fast): XCD (blockIdx%8) keeps its A rows L2-resident
  // across col passes; co-resident block pairs share the same B panel (L1).
  const int by = blockIdx.x & 63, bx = blockIdx.x >> 6;
  const int row0 = by * 64, col0 = bx * 64;

  const short* Abase = Ablk + (size_t)by * (2 * NTK) * 2048 + lane * 8;
  const short* Bbase = Bblk + (size_t)bx * (2 * NTK) * 2048 + lane * 8;

  const int nt = (3 * NTK) >> 2;   // tiles per wave: 24 (K=1024) / 12 (K=512)
  const int t0 = w * nt;

  f32x4 acc[4][4];
  #pragma unroll
  for (int s = 0; s < 4; ++s)
    #pragma unroll
    for (int u = 0; u < 4; ++u)
      acc[s][u] = (f32x4){0.f, 0.f, 0.f, 0.f};

  short8 fa[3][4], fb[3][4];

  auto ldfrag = [&](int t, short8* va, short8* vb) {
    const int ta = (t < NTK) ? t : t - NTK;          // A' = [hi|hi|lo]
    const int tb = (t < 2 * NTK) ? t : t - 2 * NTK;  // B' = [hi|lo|hi]
    const short* Ag = Abase + (size_t)ta * 2048;
    const short* Bg = Bbase + (size_t)tb * 2048;
    #pragma unroll
    for (int s = 0; s < 4; ++s) va[s] = *(const short8*)(Ag + s * 512);
    #pragma unroll
    for (int u = 0; u < 4; ++u) vb[u] = *(const short8*)(Bg + u * 512);
  };

  auto compute = [&](short8* va, short8* vb) {
    #pragma unroll
    for (int s = 0; s < 4; ++s)
      #pragma unroll
      for (int u = 0; u < 4; ++u)
        acc[s][u] = __builtin_amdgcn_mfma_f32_16x16x32_bf16(va[s], vb[u], acc[s][u], 0, 0, 0);
  };

  ldfrag(t0 + 0, fa[0], fb[0]);
  ldfrag(t0 + 1, fa[1], fb[1]);
  ldfrag(t0 + 2, fa[2], fb[2]);
  for (int i = 0; i < nt; i += 3) {
    compute(fa[0], fb[0]);
    if (i + 3 < nt) ldfrag(t0 + i + 3, fa[0], fb[0]);
    compute(fa[1], fb[1]);
    if (i + 4 < nt) ldfrag(t0 + i + 4, fa[1], fb[1]);
    compute(fa[2], fb[2]);
    if (i + 5 < nt) ldfrag(t0 + i + 5, fa[2], fb[2]);
  }

  // ---- epilogue: 2-pass cross-wave split-K reduce + bias + relu + cmax ----
  float lmax = 0.0f;

  #pragma unroll
  for (int p = 0; p < 2; ++p) {
    if (p == 1) __syncthreads();
    #pragma unroll
    for (int sp = 0; sp < 2; ++sp) {
      const int s = p * 2 + sp;
      #pragma unroll
      for (int u = 0; u < 4; ++u)
        #pragma unroll
        for (int i = 0; i < 4; ++i)
          fl[w * 2176 + (sp * 16 + rg * 4 + i) * 68 + u * 16 + rl] = acc[s][u][i];
    }
    __syncthreads();

    const int rloc = w * 8 + (lane >> 3);      // 0..31
    const int c0 = (lane & 7) * 8;
    f32x4 s0 = {0.f, 0.f, 0.f, 0.f}, s1 = {0.f, 0.f, 0.f, 0.f};
    #pragma unroll
    for (int q = 0; q < 4; ++q) {
      const float* src = fl + q * 2176 + rloc * 68 + c0;
      s0 += *(const f32x4*)src;
      s1 += *(const f32x4*)(src + 4);
    }
    const int gr = row0 + p * 32 + rloc;
    const int gc = col0 + c0;
    const f32x4 bb0 = *(const f32x4*)&bp[gc];
    const f32x4 bb1 = *(const f32x4*)&bp[gc + 4];
    f32x4 o0, o1;
    #pragma unroll
    for (int i = 0; i < 4; ++i) {
      o0[i] = fmaxf(s0[i] + bb0[i], 0.f);
      o1[i] = fmaxf(s1[i] + bb1[i], 0.f);
    }
    float* Hp = H + (size_t)gr * 512 + gc;
    *(f32x4*)Hp = o0;
    *(f32x4*)(Hp + 4) = o1;
    #pragma unroll
    for (int i = 0; i < 4; ++i) {
      if (gc + i < 500) {
        const float v = o0[i], vm = v - 1.0f;
        lmax = fmaxf(lmax, fmaxf(v * v, vm * vm));
      }
      if (gc + 4 + i < 500) {
        const float v = o1[i], vm = v - 1.0f;
        lmax = fmaxf(lmax, fmaxf(v * v, vm * vm));
      }
    }
  }

  #pragma unroll
  for (int off = 32; off; off >>= 1)
    lmax = fmaxf(lmax, __shfl_xor(lmax, off));
  if (lane == 0) atomicMax(cmax, __float_as_uint(lmax));
}

// ---------------------------------------------------------------------------
// Fused prep. Work items (cascade):
//   x : 4096*128 = 524288  (row fast-k read, coalesced)
//   W1:  512*128 =  65536  (n = idx&511 -> coalesced W reads)
//   W2:  512* 64 =  32768
//   W3:  512* 64 =  32768
//   bias 1536, cmax 3      TOTAL 656899 -> grid 2567
// ---------------------------------------------------------------------------
__device__ __forceinline__ void blk_write(
    short* __restrict__ dst, int panel, int NTK2 /*=2*NTK*/,
    int m, int kc, const float* v)
{
  const int t = kc >> 2, g = kc & 3;
  const int slot = ((m >> 4) << 6) + (g << 4) + (m & 15);
  short* o = dst + ((size_t)panel * NTK2 + t) * 2048 + slot * 8;
  short hi[8], lo[8];
  #pragma unroll
  for (int i = 0; i < 8; ++i) {
    const unsigned short h = f2bf(v[i]);
    hi[i] = (short)h;
    lo[i] = (short)f2bf(v[i] - bf2f(h));
  }
  *(uint4*)o = *(const uint4*)hi;
  *(uint4*)(o + (size_t)(NTK2 >> 1) * 2048) = *(const uint4*)lo;
}

__global__ __launch_bounds__(256) void prep_kernel(
    const float* __restrict__ x,  short* __restrict__ Ablk,
    const float* __restrict__ W1, short* __restrict__ B1blk,
    const float* __restrict__ W2, short* __restrict__ B2blk,
    const float* __restrict__ W3, short* __restrict__ B3blk,
    const float* __restrict__ b1, const float* __restrict__ b2,
    const float* __restrict__ b3, float* __restrict__ bp,
    unsigned int* __restrict__ cmax)
{
  int idx = blockIdx.x * 256 + threadIdx.x;
  if (idx < 524288) {                        // x -> Ablk
    const int row = idx >> 7, kc = idx & 127;
    float v[8];
    #pragma unroll
    for (int i = 0; i < 8; ++i) v[i] = x[(size_t)row * 1024 + kc * 8 + i];
    blk_write(Ablk, row >> 6, 64, row & 63, kc, v);
    return;
  }
  idx -= 524288;
  if (idx < 65536) {                         // W1 -> B1blk (coalesced n)
    const int n = idx & 511, kc = idx >> 9;
    float v[8];
    #pragma unroll
    for (int i = 0; i < 8; ++i)
      v[i] = (n < 500) ? W1[(size_t)(kc * 8 + i) * 500 + n] : 0.0f;
    blk_write(B1blk, n >> 6, 64, n & 63, kc, v);
    return;
  }
  idx -= 65536;
  if (idx < 32768) {                         // W2 -> B2blk
    const int n = idx & 511, kc = idx >> 9;
    float v[8];
    #pragma unroll
    for (int i = 0; i < 8; ++i) {
      const int k = kc * 8 + i;
      v[i] = (n < 500 && k < 500) ? W2[(size_t)k * 500 + n] : 0.0f;
    }
    blk_write(B2blk, n >> 6, 32, n & 63, kc, v);
    return;
  }
  idx -= 32768;
  if (idx < 32768) {                         // W3 -> B3blk
    const int n = idx & 511, kc = idx >> 9;
    float v[8];
    #pragma unroll
    for (int i = 0; i < 8; ++i) {
      const int k = kc * 8 + i;
      v[i] = (n < 500 && k < 500) ? W3[(size_t)k * 500 + n] : 0.0f;
    }
    blk_write(B3blk, n >> 6, 32, n & 63, kc, v);
    return;
  }
  idx -= 32768;
  if (idx < 1536) {                          // bias pad bp[3][512]
    const int L = idx >> 9, c = idx & 511;
    const float* src = (L == 0) ? b1 : (L == 1) ? b2 : b3;
    bp[idx] = (c < 500) ? src[c] : 0.0f;
    return;
  }
  idx -= 1536;
  if (idx < 3) cmax[idx] = 0u;               // cmax init (replay-safe)
}

// ---------------------------------------------------------------------------
// Soft top-k (2-anchor Sinkhorn collapsed to scalar fixed point). One wave
// per row; lane l owns contiguous k = 8l..8l+7. Exact early-exit: if t is
// bitwise unchanged, remaining iterations are the identity -> break.
// FINAL=0: write masked activations in blocked hi/lo layout (NTK=16).
// FINAL=1: fuse the [500x10] output GEMM + b4 (no intermediate buffer).
// ---------------------------------------------------------------------------
template<bool FINAL>
__global__ __launch_bounds__(256) void sinkhorn_kernel(
    const float* __restrict__ H, short* __restrict__ Outblk,
    const unsigned int* __restrict__ cmaxp, const int* __restrict__ sparse,
    const float* __restrict__ W4, const float* __restrict__ b4,
    float* __restrict__ out)
{
  const int w    = threadIdx.x >> 6;
  const int lane = threadIdx.x & 63;
  const int row  = blockIdx.x * 4 + w;
  const float cmax = __uint_as_float(cmaxp[0]);
  const float s    = (float)sparse[0];
  const float inv  = 1.0f / (0.1f * cmax);

  const float* Hr = H + (size_t)row * 512 + lane * 8;
  const f32x4 h0 = *(const f32x4*)Hr;
  const f32x4 h1 = *(const f32x4*)(Hr + 4);
  float h[8] = {h0[0], h0[1], h0[2], h0[3], h1[0], h1[1], h1[2], h1[3]};
  float R[8];
  #pragma unroll
  for (int j = 0; j < 8; ++j) R[j] = __expf((2.0f * h[j] - 1.0f) * inv);

  const int nval = min(max(500 - lane * 8, 0), 8);   // valid k this lane

  float t = 1.0f, A = 0.0f;
  for (int it = 0; it < 50; ++it) {
    A = 0.0f;
    #pragma unroll
    for (int j = 0; j < 8; ++j) {
      float wj = __builtin_amdgcn_rcpf(fmaf(t, R[j], 1.0f));
      if (j >= nval) wj = 0.0f;
      A += wj;
    }
    #pragma unroll
    for (int off = 32; off; off >>= 1) A += __shfl_xor(A, off);
    if (it == 49) break;
    const float tn = 0.25f * A * t * __builtin_amdgcn_rcpf(500.0f - A);
    if (__float_as_uint(tn) == __float_as_uint(t)) break;  // exact fixed point
    t = tn;
  }

  const float kA = 400.0f / A;
  float mh[8];
  #pragma unroll
  for (int j = 0; j < 8; ++j) {
    const float wj = __builtin_amdgcn_rcpf(fmaf(t, R[j], 1.0f));
    float o = h[j] * (s * (kA * wj) + (1.0f - s));
    if (j >= nval) o = 0.0f;
    mh[j] = o;
  }

  if (!FINAL) {
    short hi[8], lo[8];
    #pragma unroll
    for (int j = 0; j < 8; ++j) {
      const unsigned short hh = f2bf(mh[j]);
      hi[j] = (short)hh;
      lo[j] = (short)f2bf(mh[j] - bf2f(hh));
    }
    const int p = row >> 6, m = row & 63;
    const int tt = lane >> 2, g = lane & 3;
    const int slot = ((m >> 4) << 6) + (g << 4) + (m & 15);
    short* o = Outblk + ((size_t)p * 32 + tt) * 2048 + slot * 8;
    *(uint4*)o           = *(const uint4*)hi;
    *(uint4*)(o + 32768) = *(const uint4*)lo;   // lo tiles: +NTK(16)*2048
  } else {
    float acc[10];
    #pragma unroll
    for (int o = 0; o < 10; ++o) acc[o] = 0.0f;
    const float* Wr = W4 + (size_t)lane * 80;
    #pragma unroll
    for (int j = 0; j < 8; ++j) {
      if (j < nval) {
        #pragma unroll
        for (int o = 0; o < 10; ++o) acc[o] = fmaf(mh[j], Wr[j * 10 + o], acc[o]);
      }
    }
    #pragma unroll
    for (int o = 0; o < 10; ++o) {
      #pragma unroll
      for (int off = 32; off; off >>= 1) acc[o] += __shfl_xor(acc[o], off);
    }
    if (lane == 0) {
      #pragma unroll
      for (int o = 0; o < 10; ++o) out[(size_t)row * 10 + o] = acc[o] + b4[o];
    }
  }
}

extern "C" void kernel_launch(void* const* d_in, const int* in_sizes, int n_in,
                              void* d_out, int out_size, void* d_ws, size_t ws_size,
                              hipStream_t stream)
{
  const float* x  = (const float*)d_in[0];
  const float* W1 = (const float*)d_in[1];
  const float* b1 = (const float*)d_in[2];
  const float* W2 = (const float*)d_in[3];
  const float* b2 = (const float*)d_in[4];
  const float* W3 = (const float*)d_in[5];
  const float* b3 = (const float*)d_in[6];
  const float* W4 = (const float*)d_in[7];
  const float* b4 = (const float*)d_in[8];
  const int* sparse = (const int*)d_in[9];

  float* out = (float*)d_out;
  char* ws = (char*)d_ws;

  unsigned int* cmax = (unsigned int*)ws;                        // 3 slots
  float* bp    = (float*)(ws + 256);                             // [3][512]
  short* Ablk  = (short*)(ws + 8192);                            // 16MB
  short* B1blk = Ablk  + (size_t)64 * 64 * 2048;                 // 2MB
  short* B2blk = B1blk + (size_t)8 * 64 * 2048;                  // 1MB
  short* B3blk = B2blk + (size_t)8 * 32 * 2048;                  // 1MB
  float* H     = (float*)(B3blk + (size_t)8 * 32 * 2048);        // 8MB
  short* Hmblk = (short*)(H + (size_t)4096 * 512);               // 8MB

  prep_kernel<<<2567, 256, 0, stream>>>(x, Ablk, W1, B1blk, W2, B2blk,
                                        W3, B3blk, b1, b2, b3, bp, cmax);

  gemm_mfma<<<512, 256, 0, stream>>>(Ablk, B1blk, 32, bp, H, cmax + 0);
  sinkhorn_kernel<false><<<1024, 256, 0, stream>>>(H, Hmblk, cmax + 0, sparse,
                                                   nullptr, nullptr, nullptr);

  gemm_mfma<<<512, 256, 0, stream>>>(Hmblk, B2blk, 16, bp + 512, H, cmax + 1);
  sinkhorn_kernel<false><<<1024, 256, 0, stream>>>(H, Hmblk, cmax + 1, sparse,
                                                   nullptr, nullptr, nullptr);

  gemm_mfma<<<512, 256, 0, stream>>>(Hmblk, B3blk, 16, bp + 1024, H, cmax + 2);
  sinkhorn_kernel<true><<<1024, 256, 0, stream>>>(H, nullptr, cmax + 2, sparse,
                                                  W4, b4, out);
}

// Round 7
// 135.183 us; speedup vs baseline: 5.8122x; 1.4119x over previous
//
#include <hip/hip_runtime.h>
#include <math.h>

// ---------------------------------------------------------------------------
// NeuralNet_62045097558546 on MI355X (gfx950)
// 3x (GEMM+bias+ReLU+cmax -> soft-topk mask) -> GEMM+bias
// GEMMs: bf16 MFMA split precision, C = Ahi*Bhi + Ahi*Blo + Alo*Bhi as one
// bf16 GEMM over K' = 3K. Physical storage: compact [hi(NTK) | lo(NTK)] tiles.
// Logical tile t: A (=[hi|hi|lo]): ta = t<NTK ? t : t-NTK
//                B (=[hi|lo|hi]): tb = t<2NTK ? t : t-2NTK
//
// FRAGMENT-ORDER BLOCKED LAYOUT (built by prep/sinkhorn, read by gemm):
//   panel p (64 rows) -> tile t (32 k') -> slot s = (m>>4)*64 + g*16 + (m&15)
//   (8 shorts: row m, k-chunk g) => fragment load for sub-tile s16 is ONE
//   contiguous 1KB block: lane l reads slot s16*64 + l  (m=s16*16+(l&15),
//   g=l>>4; A and B use the SAME per-lane k-window -> k-mapping-proof).
//
// K-loop: NO LDS, no barriers, no atomics. COMPILE-TIME unrolled (template
// NTK) 3-stage register pipeline -> ~24 loads in flight, counted vmcnt.
// Per-wave split-K (4 waves = 4 k'-quarters); LDS only for split-K epilogue.
// Block max -> cmaxArr[block]; consumers reduce the 512-entry array.
// ---------------------------------------------------------------------------

typedef __attribute__((ext_vector_type(8))) short short8;
typedef __attribute__((ext_vector_type(4))) float f32x4;

__device__ __forceinline__ unsigned short f2bf(float f) {
  unsigned u = __float_as_uint(f);
  u += 0x7fffu + ((u >> 16) & 1u);
  return (unsigned short)(u >> 16);
}
__device__ __forceinline__ float bf2f(unsigned short s) {
  return __uint_as_float(((unsigned)s) << 16);
}

#define LDF(t, va, vb)                                                   \
  do {                                                                   \
    const int ta_ = ((t) < NTK) ? (t) : (t) - NTK;                       \
    const int tb_ = ((t) < 2 * NTK) ? (t) : (t) - 2 * NTK;               \
    const short* Ag_ = Abase + (size_t)ta_ * 2048;                       \
    const short* Bg_ = Bbase + (size_t)tb_ * 2048;                       \
    va[0] = *(const short8*)(Ag_);                                       \
    va[1] = *(const short8*)(Ag_ + 512);                                 \
    va[2] = *(const short8*)(Ag_ + 1024);                                \
    va[3] = *(const short8*)(Ag_ + 1536);                                \
    vb[0] = *(const short8*)(Bg_);                                       \
    vb[1] = *(const short8*)(Bg_ + 512);                                 \
    vb[2] = *(const short8*)(Bg_ + 1024);                                \
    vb[3] = *(const short8*)(Bg_ + 1536);                                \
  } while (0)

#define CMP(va, vb)                                                      \
  do {                                                                   \
    _Pragma("unroll")                                                    \
    for (int s_ = 0; s_ < 4; ++s_)                                       \
      _Pragma("unroll")                                                  \
      for (int u_ = 0; u_ < 4; ++u_)                                     \
        acc[s_][u_] = __builtin_amdgcn_mfma_f32_16x16x32_bf16(           \
            va[s_], vb[u_], acc[s_][u_], 0, 0, 0);                       \
  } while (0)

template <int NTK>
__global__ __launch_bounds__(256, 2) void gemm_mfma(
    const short* __restrict__ Ablk, const short* __restrict__ Bblk,
    const float* __restrict__ bp, float* __restrict__ H,
    float* __restrict__ cmaxArr)
{
  __shared__ __align__(16) float fl[8704];   // epilogue: 4 x [32][68]
  __shared__ float red4[4];

  const int tid  = threadIdx.x;
  const int lane = tid & 63, w = tid >> 6;
  const int rg = lane >> 4, rl = lane & 15;

  // by fast: XCD (blockIdx%8) keeps its A row-panels L2-resident across
  // col passes.
  const int by = blockIdx.x & 63, bx = blockIdx.x >> 6;
  const int row0 = by * 64, col0 = bx * 64;

  const short* Abase = Ablk + (size_t)by * (2 * NTK) * 2048 + lane * 8;
  const short* Bbase = Bblk + (size_t)bx * (2 * NTK) * 2048 + lane * 8;

  constexpr int nt = (3 * NTK) >> 2;   // 24 (K=1024) / 12 (K=512)
  const int t0 = w * nt;

  f32x4 acc[4][4];
  #pragma unroll
  for (int s = 0; s < 4; ++s)
    #pragma unroll
    for (int u = 0; u < 4; ++u)
      acc[s][u] = (f32x4){0.f, 0.f, 0.f, 0.f};

  short8 A0[4], B0[4], A1[4], B1[4], A2[4], B2[4];
  LDF(t0 + 0, A0, B0);
  LDF(t0 + 1, A1, B1);
  LDF(t0 + 2, A2, B2);
  #pragma unroll
  for (int i = 0; i < nt; i += 3) {
    CMP(A0, B0);
    if (i + 3 < nt) LDF(t0 + i + 3, A0, B0);
    CMP(A1, B1);
    if (i + 4 < nt) LDF(t0 + i + 4, A1, B1);
    CMP(A2, B2);
    if (i + 5 < nt) LDF(t0 + i + 5, A2, B2);
  }

  // ---- epilogue: 2-pass cross-wave split-K reduce + bias + relu + cmax ----
  float lmax = 0.0f;

  #pragma unroll
  for (int p = 0; p < 2; ++p) {
    if (p == 1) __syncthreads();
    #pragma unroll
    for (int sp = 0; sp < 2; ++sp) {
      const int s = p * 2 + sp;
      #pragma unroll
      for (int u = 0; u < 4; ++u)
        #pragma unroll
        for (int i = 0; i < 4; ++i)
          fl[w * 2176 + (sp * 16 + rg * 4 + i) * 68 + u * 16 + rl] = acc[s][u][i];
    }
    __syncthreads();

    const int rloc = w * 8 + (lane >> 3);      // 0..31
    const int c0 = (lane & 7) * 8;
    f32x4 s0 = {0.f, 0.f, 0.f, 0.f}, s1 = {0.f, 0.f, 0.f, 0.f};
    #pragma unroll
    for (int q = 0; q < 4; ++q) {
      const float* src = fl + q * 2176 + rloc * 68 + c0;
      s0 += *(const f32x4*)src;
      s1 += *(const f32x4*)(src + 4);
    }
    const int gr = row0 + p * 32 + rloc;
    const int gc = col0 + c0;
    const f32x4 bb0 = *(const f32x4*)&bp[gc];
    const f32x4 bb1 = *(const f32x4*)&bp[gc + 4];
    f32x4 o0, o1;
    #pragma unroll
    for (int i = 0; i < 4; ++i) {
      o0[i] = fmaxf(s0[i] + bb0[i], 0.f);
      o1[i] = fmaxf(s1[i] + bb1[i], 0.f);
    }
    float* Hp = H + (size_t)gr * 512 + gc;
    *(f32x4*)Hp = o0;
    *(f32x4*)(Hp + 4) = o1;
    #pragma unroll
    for (int i = 0; i < 4; ++i) {
      if (gc + i < 500) {
        const float v = o0[i], vm = v - 1.0f;
        lmax = fmaxf(lmax, fmaxf(v * v, vm * vm));
      }
      if (gc + 4 + i < 500) {
        const float v = o1[i], vm = v - 1.0f;
        lmax = fmaxf(lmax, fmaxf(v * v, vm * vm));
      }
    }
  }

  // block max -> cmaxArr[block] (no global atomics)
  #pragma unroll
  for (int off = 32; off; off >>= 1)
    lmax = fmaxf(lmax, __shfl_xor(lmax, off));
  if (lane == 0) red4[w] = lmax;
  __syncthreads();
  if (tid == 0)
    cmaxArr[blockIdx.x] =
        fmaxf(fmaxf(red4[0], red4[1]), fmaxf(red4[2], red4[3]));
}

// ---------------------------------------------------------------------------
// Fused prep. Work cascade:
//   x : 524288, W1: 65536, W2: 32768, W3: 32768, bias: 1536 -> 656896 = 2566*256
// ---------------------------------------------------------------------------
__device__ __forceinline__ void blk_write(
    short* __restrict__ dst, int panel, int NTK2 /*=2*NTK*/,
    int m, int kc, const float* v)
{
  const int t = kc >> 2, g = kc & 3;
  const int slot = ((m >> 4) << 6) + (g << 4) + (m & 15);
  short* o = dst + ((size_t)panel * NTK2 + t) * 2048 + slot * 8;
  short hi[8], lo[8];
  #pragma unroll
  for (int i = 0; i < 8; ++i) {
    const unsigned short h = f2bf(v[i]);
    hi[i] = (short)h;
    lo[i] = (short)f2bf(v[i] - bf2f(h));
  }
  *(uint4*)o = *(const uint4*)hi;
  *(uint4*)(o + (size_t)(NTK2 >> 1) * 2048) = *(const uint4*)lo;
}

__global__ __launch_bounds__(256) void prep_kernel(
    const float* __restrict__ x,  short* __restrict__ Ablk,
    const float* __restrict__ W1, short* __restrict__ B1blk,
    const float* __restrict__ W2, short* __restrict__ B2blk,
    const float* __restrict__ W3, short* __restrict__ B3blk,
    const float* __restrict__ b1, const float* __restrict__ b2,
    const float* __restrict__ b3, float* __restrict__ bp)
{
  int idx = blockIdx.x * 256 + threadIdx.x;
  if (idx < 524288) {                        // x -> Ablk
    const int row = idx >> 7, kc = idx & 127;
    float v[8];
    #pragma unroll
    for (int i = 0; i < 8; ++i) v[i] = x[(size_t)row * 1024 + kc * 8 + i];
    blk_write(Ablk, row >> 6, 64, row & 63, kc, v);
    return;
  }
  idx -= 524288;
  if (idx < 65536) {                         // W1 -> B1blk (coalesced n)
    const int n = idx & 511, kc = idx >> 9;
    float v[8];
    #pragma unroll
    for (int i = 0; i < 8; ++i)
      v[i] = (n < 500) ? W1[(size_t)(kc * 8 + i) * 500 + n] : 0.0f;
    blk_write(B1blk, n >> 6, 64, n & 63, kc, v);
    return;
  }
  idx -= 65536;
  if (idx < 32768) {                         // W2 -> B2blk
    const int n = idx & 511, kc = idx >> 9;
    float v[8];
    #pragma unroll
    for (int i = 0; i < 8; ++i) {
      const int k = kc * 8 + i;
      v[i] = (n < 500 && k < 500) ? W2[(size_t)k * 500 + n] : 0.0f;
    }
    blk_write(B2blk, n >> 6, 32, n & 63, kc, v);
    return;
  }
  idx -= 32768;
  if (idx < 32768) {                         // W3 -> B3blk
    const int n = idx & 511, kc = idx >> 9;
    float v[8];
    #pragma unroll
    for (int i = 0; i < 8; ++i) {
      const int k = kc * 8 + i;
      v[i] = (n < 500 && k < 500) ? W3[(size_t)k * 500 + n] : 0.0f;
    }
    blk_write(B3blk, n >> 6, 32, n & 63, kc, v);
    return;
  }
  idx -= 32768;
  if (idx < 1536) {                          // bias pad bp[3][512]
    const int L = idx >> 9, c = idx & 511;
    const float* src = (L == 0) ? b1 : (L == 1) ? b2 : b3;
    bp[idx] = (c < 500) ? src[c] : 0.0f;
  }
}

// ---------------------------------------------------------------------------
// Soft top-k (2-anchor Sinkhorn collapsed to scalar fixed point). One wave
// per row; lane l owns k = 8l..8l+7. cmax = wave-reduce of cmaxArr[512].
// Exact early-exit on bitwise-stationary t.
// FINAL=0: write masked activations in blocked hi/lo layout (NTK=16).
// FINAL=1: fuse the [500x10] output GEMM + b4.
// ---------------------------------------------------------------------------
template<bool FINAL>
__global__ __launch_bounds__(256) void sinkhorn_kernel(
    const float* __restrict__ H, short* __restrict__ Outblk,
    const float* __restrict__ cmaxArr, const int* __restrict__ sparse,
    const float* __restrict__ W4, const float* __restrict__ b4,
    float* __restrict__ out)
{
  const int w    = threadIdx.x >> 6;
  const int lane = threadIdx.x & 63;
  const int row  = blockIdx.x * 4 + w;

  // global cmax: reduce the 512 per-block maxima (2KB, L2-hot)
  const f32x4 c0 = *(const f32x4*)&cmaxArr[lane * 8];
  const f32x4 c1 = *(const f32x4*)&cmaxArr[lane * 8 + 4];
  float cmax = fmaxf(fmaxf(fmaxf(c0[0], c0[1]), fmaxf(c0[2], c0[3])),
                     fmaxf(fmaxf(c1[0], c1[1]), fmaxf(c1[2], c1[3])));
  #pragma unroll
  for (int off = 32; off; off >>= 1)
    cmax = fmaxf(cmax, __shfl_xor(cmax, off));

  const float s    = (float)sparse[0];
  const float inv  = 1.0f / (0.1f * cmax);

  const float* Hr = H + (size_t)row * 512 + lane * 8;
  const f32x4 h0 = *(const f32x4*)Hr;
  const f32x4 h1 = *(const f32x4*)(Hr + 4);
  float h[8] = {h0[0], h0[1], h0[2], h0[3], h1[0], h1[1], h1[2], h1[3]};
  float R[8];
  #pragma unroll
  for (int j = 0; j < 8; ++j) R[j] = __expf((2.0f * h[j] - 1.0f) * inv);

  const int nval = min(max(500 - lane * 8, 0), 8);   // valid k this lane

  float t = 1.0f, A = 0.0f;
  for (int it = 0; it < 50; ++it) {
    A = 0.0f;
    #pragma unroll
    for (int j = 0; j < 8; ++j) {
      float wj = __builtin_amdgcn_rcpf(fmaf(t, R[j], 1.0f));
      if (j >= nval) wj = 0.0f;
      A += wj;
    }
    #pragma unroll
    for (int off = 32; off; off >>= 1) A += __shfl_xor(A, off);
    if (it == 49) break;
    const float tn = 0.25f * A * t * __builtin_amdgcn_rcpf(500.0f - A);
    if (__float_as_uint(tn) == __float_as_uint(t)) break;  // exact fixed point
    t = tn;
  }

  const float kA = 400.0f / A;
  float mh[8];
  #pragma unroll
  for (int j = 0; j < 8; ++j) {
    const float wj = __builtin_amdgcn_rcpf(fmaf(t, R[j], 1.0f));
    float o = h[j] * (s * (kA * wj) + (1.0f - s));
    if (j >= nval) o = 0.0f;
    mh[j] = o;
  }

  if (!FINAL) {
    short hi[8], lo[8];
    #pragma unroll
    for (int j = 0; j < 8; ++j) {
      const unsigned short hh = f2bf(mh[j]);
      hi[j] = (short)hh;
      lo[j] = (short)f2bf(mh[j] - bf2f(hh));
    }
    const int p = row >> 6, m = row & 63;
    const int tt = lane >> 2, g = lane & 3;
    const int slot = ((m >> 4) << 6) + (g << 4) + (m & 15);
    short* o = Outblk + ((size_t)p * 32 + tt) * 2048 + slot * 8;
    *(uint4*)o           = *(const uint4*)hi;
    *(uint4*)(o + 32768) = *(const uint4*)lo;   // lo tiles: +NTK(16)*2048
  } else {
    float acc[10];
    #pragma unroll
    for (int o = 0; o < 10; ++o) acc[o] = 0.0f;
    const float* Wr = W4 + (size_t)lane * 80;
    #pragma unroll
    for (int j = 0; j < 8; ++j) {
      if (j < nval) {
        #pragma unroll
        for (int o = 0; o < 10; ++o) acc[o] = fmaf(mh[j], Wr[j * 10 + o], acc[o]);
      }
    }
    #pragma unroll
    for (int o = 0; o < 10; ++o) {
      #pragma unroll
      for (int off = 32; off; off >>= 1) acc[o] += __shfl_xor(acc[o], off);
    }
    if (lane == 0) {
      #pragma unroll
      for (int o = 0; o < 10; ++o) out[(size_t)row * 10 + o] = acc[o] + b4[o];
    }
  }
}

extern "C" void kernel_launch(void* const* d_in, const int* in_sizes, int n_in,
                              void* d_out, int out_size, void* d_ws, size_t ws_size,
                              hipStream_t stream)
{
  const float* x  = (const float*)d_in[0];
  const float* W1 = (const float*)d_in[1];
  const float* b1 = (const float*)d_in[2];
  const float* W2 = (const float*)d_in[3];
  const float* b2 = (const float*)d_in[4];
  const float* W3 = (const float*)d_in[5];
  const float* b3 = (const float*)d_in[6];
  const float* W4 = (const float*)d_in[7];
  const float* b4 = (const float*)d_in[8];
  const int* sparse = (const int*)d_in[9];

  float* out = (float*)d_out;
  char* ws = (char*)d_ws;

  float* cmaxA = (float*)ws;                                     // [3][512]
  float* bp    = (float*)(ws + 8192);                            // [3][512]
  short* Ablk  = (short*)(ws + 16384);                           // 16MB
  short* B1blk = Ablk  + (size_t)64 * 64 * 2048;                 // 2MB
  short* B2blk = B1blk + (size_t)8 * 64 * 2048;                  // 1MB
  short* B3blk = B2blk + (size_t)8 * 32 * 2048;                  // 1MB
  float* H     = (float*)(B3blk + (size_t)8 * 32 * 2048);        // 8MB
  short* Hmblk = (short*)(H + (size_t)4096 * 512);               // 8MB

  prep_kernel<<<2566, 256, 0, stream>>>(x, Ablk, W1, B1blk, W2, B2blk,
                                        W3, B3blk, b1, b2, b3, bp);

  gemm_mfma<32><<<512, 256, 0, stream>>>(Ablk, B1blk, bp, H, cmaxA);
  sinkhorn_kernel<false><<<1024, 256, 0, stream>>>(H, Hmblk, cmaxA, sparse,
                                                   nullptr, nullptr, nullptr);

  gemm_mfma<16><<<512, 256, 0, stream>>>(Hmblk, B2blk, bp + 512, H, cmaxA + 512);
  sinkhorn_kernel<false><<<1024, 256, 0, stream>>>(H, Hmblk, cmaxA + 512, sparse,
                                                   nullptr, nullptr, nullptr);

  gemm_mfma<16><<<512, 256, 0, stream>>>(Hmblk, B3blk, bp + 1024, H, cmaxA + 1024);
  sinkhorn_kernel<true><<<1024, 256, 0, stream>>>(H, nullptr, cmaxA + 1024, sparse,
                                                  W4, b4, out);
}